// Round 8
// baseline (274.605 us; speedup 1.0000x reference)
//
#include <hip/hip_runtime.h>
#include <hip/hip_bf16.h>
#include <stdint.h>
#include <stddef.h>

#define HW 262144          // 512*512
#define EPSF 1e-5f

typedef __hip_bfloat16 bf16;

__device__ __forceinline__ float us2f(uint32_t u){
  union { uint32_t i; float f; } c; c.i = u << 16; return c.f;
}
__device__ __forceinline__ ushort f2bu(float v){
  union { bf16 h; ushort u; } c; c.h = __float2bfloat16(v); return c.u;
}
__device__ __forceinline__ float lrelu(float v){ return v > 0.0f ? v : 0.01f * v; }
__device__ __forceinline__ uint32_t umax2(uint32_t a, uint32_t b){ return a > b ? a : b; }

// ---------------------------------------------------------------------------
// K0a: quantize x to level k = rint(x*255/16), materialize reflect-padded u8
// plane [6][522 rows][pitch 528]
// ---------------------------------------------------------------------------
__global__ __launch_bounds__(256) void k_quant_pad(const float* __restrict__ x,
                                                   uint8_t* __restrict__ qpad){
  int idx = blockIdx.x * 256 + threadIdx.x;
  if (idx >= 6 * 522 * 522) return;
  int pw = idx % 522; int t = idx / 522; int ph = t % 522; int img = t / 522;
  int h = ph - 5; h = h < 0 ? -h : h; if (h > 511) h = 1022 - h;
  int w = pw - 5; w = w < 0 ? -w : w; if (w > 511) w = 1022 - w;
  float v = x[img * HW + h * 512 + w];
  int k = (int)rintf((v * 255.0f) / 16.0f);   // round-half-even, matches jnp.round
  qpad[img * (522 * 528) + ph * 528 + pw] = (uint8_t)k;
}

// ---------------------------------------------------------------------------
// K0b: 11x11 mode filter (LDS tile, rolled loops to avoid VGPR spill — r4/r5).
// ---------------------------------------------------------------------------
__global__ __launch_bounds__(256) void k_mode(const uint8_t* __restrict__ qpad,
                                              uint8_t* __restrict__ xm){
  __shared__ uint8_t tile[14 * 528];          // 7392 B
  int tid = threadIdx.x;
  int img = blockIdx.x >> 7;
  int h0  = (blockIdx.x & 127) << 2;          // first output row of block
  {
    const uint4* g4 = (const uint4*)(qpad + img * (522 * 528) + h0 * 528);
    uint4* t4 = (uint4*)tile;
    t4[tid] = g4[tid];                        // 0..255
    if (tid < 206) t4[tid + 256] = g4[tid + 256];   // 256..461 (462 total)
  }
  __syncthreads();
  int r4 = tid >> 6;                          // row within block 0..3
  int w0 = (tid & 63) << 3;                   // 0..504
  const uint8_t* base = tile + r4 * 528 + w0;
  uint32_t c0 = 0, c1 = 0, c2 = 0, c3 = 0, c4 = 0;
#define HINC(q) { uint32_t inc_ = 1u << (((q) & 3u) << 3); uint32_t rr_ = (q) >> 2; \
    c0 += (rr_==0u)?inc_:0u; c1 += (rr_==1u)?inc_:0u; c2 += (rr_==2u)?inc_:0u; \
    c3 += (rr_==3u)?inc_:0u; c4 += (rr_==4u)?inc_:0u; }
#define HDEC(q) { uint32_t inc_ = 1u << (((q) & 3u) << 3); uint32_t rr_ = (q) >> 2; \
    c0 -= (rr_==0u)?inc_:0u; c1 -= (rr_==1u)?inc_:0u; c2 -= (rr_==2u)?inc_:0u; \
    c3 -= (rr_==3u)?inc_:0u; c4 -= (rr_==4u)?inc_:0u; }
  #pragma unroll 1
  for (int r = 0; r < 11; ++r){
    const uint8_t* row = base + r * 528;
    #pragma unroll
    for (int j = 0; j < 11; ++j){ uint32_t q = row[j]; HINC(q); }
  }
  uint64_t packed = 0;
  #pragma unroll 1
  for (int s = 0; s < 8; ++s){
    // key(l) = (cnt<<5) | (16-l); max key -> max cnt, tie -> smallest level
#define KEY(reg, sh, l) (((((reg) >> (sh)) & 0xffu) << 5) | (16u - (uint32_t)(l)))
    uint32_t m0 = umax2(umax2(KEY(c0,0,0),  KEY(c0,8,1)),  umax2(KEY(c0,16,2),  KEY(c0,24,3)));
    uint32_t m1 = umax2(umax2(KEY(c1,0,4),  KEY(c1,8,5)),  umax2(KEY(c1,16,6),  KEY(c1,24,7)));
    uint32_t m2 = umax2(umax2(KEY(c2,0,8),  KEY(c2,8,9)),  umax2(KEY(c2,16,10), KEY(c2,24,11)));
    uint32_t m3 = umax2(umax2(KEY(c3,0,12), KEY(c3,8,13)), umax2(KEY(c3,16,14), KEY(c3,24,15)));
    uint32_t m  = umax2(umax2(umax2(m0, m1), umax2(m2, m3)), KEY(c4,0,16));
#undef KEY
    uint32_t lvl = 16u - (m & 31u);
    packed |= ((uint64_t)lvl) << (8 * s);
    if (s < 7){
      #pragma unroll
      for (int r = 0; r < 11; ++r){
        uint32_t qo = base[r * 528 + s];      HDEC(qo);
        uint32_t qn = base[r * 528 + s + 11]; HINC(qn);
      }
    }
  }
#undef HINC
#undef HDEC
  *(uint64_t*)(xm + img * HW + (h0 + r4) * 512 + w0) = packed;
}

// ---------------------------------------------------------------------------
// block reduction of per-thread su[16]/sq[16] -> partials[block][32]
// ---------------------------------------------------------------------------
__device__ __forceinline__ void reduce16(float* su, float* sq, float* __restrict__ partials){
  __shared__ float lsum[32];
  int tid = threadIdx.x;
  if (tid < 32) lsum[tid] = 0.0f;
  __syncthreads();
  #pragma unroll
  for (int o = 0; o < 16; ++o){
    float s = su[o], q = sq[o];
    #pragma unroll
    for (int off = 32; off >= 1; off >>= 1){
      s += __shfl_xor(s, off);
      q += __shfl_xor(q, off);
    }
    if ((tid & 63) == 0){ atomicAdd(&lsum[o], s); atomicAdd(&lsum[16 + o], q); }
  }
  __syncthreads();
  if (tid < 32) partials[blockIdx.x * 32 + tid] = lsum[tid];
}

// ---------------------------------------------------------------------------
// per-block BN-param computation from a [512][32] partials buffer.
// Deterministic order -> bit-identical (sc,sh) in every block.
// prm (LDS, 32 floats): prm[o]=scale, prm[16+o]=shift.
// ---------------------------------------------------------------------------
__device__ __forceinline__ void prep_params_pair(const float* __restrict__ Pp,
                                                 const float* __restrict__ g,
                                                 const float* __restrict__ bb,
                                                 float* prm){
  __shared__ float part[8][32];
  __shared__ double tot[32];
  int tid = threadIdx.x;
  int o = tid & 31, gg = tid >> 5;
  float s = 0.0f;
  #pragma unroll 1
  for (int j = 0; j < 64; ++j) s += Pp[(gg * 64 + j) * 32 + o];
  part[gg][o] = s;
  __syncthreads();
  if (tid < 32){
    double t = 0.0;
    #pragma unroll
    for (int k = 0; k < 8; ++k) t += (double)part[k][tid];
    tot[tid] = t;
  }
  __syncthreads();
  if (tid < 16){
    double m = tot[tid] / 524288.0;
    double v = tot[16 + tid] / 524288.0 - m * m;
    float sc = g[tid] / sqrtf((float)v + EPSF);
    prm[tid] = sc;
    prm[16 + tid] = bb[tid] - (float)m * sc;
  }
  __syncthreads();
}

// ---------------------------------------------------------------------------
// K1: stats of p1 = conv1x1(xm). 4 px/thread. grid 512 x 256.
// ---------------------------------------------------------------------------
__global__ __launch_bounds__(256) void k_stats1(const uint8_t* __restrict__ xm,
                                                const float* __restrict__ w1,
                                                const float* __restrict__ b1,
                                                float* __restrict__ partials){
  int t0 = (blockIdx.x * 256 + threadIdx.x) << 2;
  int b = t0 >> 18, hw = t0 & (HW - 1);
  uint32_t q0 = *(const uint32_t*)(xm + (b * 3 + 0) * HW + hw);
  uint32_t q1 = *(const uint32_t*)(xm + (b * 3 + 1) * HW + hw);
  uint32_t q2 = *(const uint32_t*)(xm + (b * 3 + 2) * HW + hw);
  float su[16], sq[16];
  #pragma unroll
  for (int o = 0; o < 16; ++o){ su[o] = 0.0f; sq[o] = 0.0f; }
  #pragma unroll
  for (int px = 0; px < 4; ++px){
    float x0 = (float)((q0 >> (8 * px)) & 0xffu) * 0.0625f;
    float x1 = (float)((q1 >> (8 * px)) & 0xffu) * 0.0625f;
    float x2 = (float)((q2 >> (8 * px)) & 0xffu) * 0.0625f;
    #pragma unroll
    for (int o = 0; o < 16; ++o){
      float v = b1[o] + w1[o*3]*x0 + w1[o*3+1]*x1 + w1[o*3+2]*x2;
      su[o] += v; sq[o] += v * v;
    }
  }
  reduce16(su, sq, partials);
}

// ---------------------------------------------------------------------------
// K2: prologue bn1 params from Pp1; recompute p1, bn1+lrelu, p2 = conv1x1,
// stats of p2 -> Pp2. 4 px/thread.
// ---------------------------------------------------------------------------
__global__ __launch_bounds__(256) void k_stats2(const uint8_t* __restrict__ xm,
                                                const float* __restrict__ w1,
                                                const float* __restrict__ b1,
                                                const float* __restrict__ w2,
                                                const float* __restrict__ b2,
                                                const float* __restrict__ Pp1,
                                                const float* __restrict__ g1,
                                                const float* __restrict__ be1,
                                                float* __restrict__ partials){
  __shared__ float prm[32];
  prep_params_pair(Pp1, g1, be1, prm);
  int t0 = (blockIdx.x * 256 + threadIdx.x) << 2;
  int b = t0 >> 18, hw = t0 & (HW - 1);
  uint32_t q0 = *(const uint32_t*)(xm + (b * 3 + 0) * HW + hw);
  uint32_t q1 = *(const uint32_t*)(xm + (b * 3 + 1) * HW + hw);
  uint32_t q2 = *(const uint32_t*)(xm + (b * 3 + 2) * HW + hw);
  float tv[4][16];
  #pragma unroll
  for (int px = 0; px < 4; ++px){
    float x0 = (float)((q0 >> (8 * px)) & 0xffu) * 0.0625f;
    float x1 = (float)((q1 >> (8 * px)) & 0xffu) * 0.0625f;
    float x2 = (float)((q2 >> (8 * px)) & 0xffu) * 0.0625f;
    #pragma unroll
    for (int o = 0; o < 16; ++o){
      float v = b1[o] + w1[o*3]*x0 + w1[o*3+1]*x1 + w1[o*3+2]*x2;
      tv[px][o] = lrelu(v * prm[o] + prm[16 + o]);
    }
  }
  float su[16], sq[16];
  #pragma unroll
  for (int o = 0; o < 16; ++o){ su[o] = 0.0f; sq[o] = 0.0f; }
  #pragma unroll
  for (int o = 0; o < 16; ++o){
    #pragma unroll
    for (int px = 0; px < 4; ++px){
      float acc = b2[o];
      #pragma unroll
      for (int c = 0; c < 16; ++c) acc = fmaf(w2[o*16 + c], tv[px][c], acc);
      su[o] += acc; sq[o] += acc * acc;
    }
  }
  reduce16(su, sq, partials);
}

// ---------------------------------------------------------------------------
// K3: prologue bn1 (Pp1) + bn2 (Pp2) params; recompute p2, bn2+lrelu,
// write p (bf16). 4 px/thread.
// ---------------------------------------------------------------------------
__global__ __launch_bounds__(256) void k_prep(const uint8_t* __restrict__ xm,
                                              const float* __restrict__ w1,
                                              const float* __restrict__ b1,
                                              const float* __restrict__ w2,
                                              const float* __restrict__ b2,
                                              const float* __restrict__ Pp1,
                                              const float* __restrict__ g1,
                                              const float* __restrict__ be1,
                                              const float* __restrict__ Pp2,
                                              const float* __restrict__ g2,
                                              const float* __restrict__ be2,
                                              bf16* __restrict__ p){
  __shared__ float prm1[32], prm2[32];
  prep_params_pair(Pp1, g1, be1, prm1);
  prep_params_pair(Pp2, g2, be2, prm2);
  int t0 = (blockIdx.x * 256 + threadIdx.x) << 2;
  int b = t0 >> 18, hw = t0 & (HW - 1);
  uint32_t q0 = *(const uint32_t*)(xm + (b * 3 + 0) * HW + hw);
  uint32_t q1 = *(const uint32_t*)(xm + (b * 3 + 1) * HW + hw);
  uint32_t q2 = *(const uint32_t*)(xm + (b * 3 + 2) * HW + hw);
  float tv[4][16];
  #pragma unroll
  for (int px = 0; px < 4; ++px){
    float x0 = (float)((q0 >> (8 * px)) & 0xffu) * 0.0625f;
    float x1 = (float)((q1 >> (8 * px)) & 0xffu) * 0.0625f;
    float x2 = (float)((q2 >> (8 * px)) & 0xffu) * 0.0625f;
    #pragma unroll
    for (int o = 0; o < 16; ++o){
      float v = b1[o] + w1[o*3]*x0 + w1[o*3+1]*x1 + w1[o*3+2]*x2;
      tv[px][o] = lrelu(v * prm1[o] + prm1[16 + o]);
    }
  }
  #pragma unroll
  for (int o = 0; o < 16; ++o){
    uint32_t w01 = 0, w23 = 0;
    #pragma unroll
    for (int px = 0; px < 4; ++px){
      float acc = b2[o];
      #pragma unroll
      for (int c = 0; c < 16; ++c) acc = fmaf(w2[o*16 + c], tv[px][c], acc);
      float v = lrelu(acc * prm2[o] + prm2[16 + o]);
      uint32_t bits = (uint32_t)f2bu(v);
      if (px == 0) w01 = bits;
      else if (px == 1) w01 |= bits << 16;
      else if (px == 2) w23 = bits;
      else w23 |= bits << 16;
    }
    uint2 ov; ov.x = w01; ov.y = w23;
    *(uint2*)((ushort*)p + (b * 16 + o) * HW + hw) = ov;
  }
}

// ---------------------------------------------------------------------------
// row loader for depthwise conv: 10 values (cols w0-1 .. w0+8), zero-padded.
// ---------------------------------------------------------------------------
__device__ __forceinline__ void load_row10(const ushort* __restrict__ rp, int w0, float* v){
  uint4 cc = *(const uint4*)(rp + w0);
  uint32_t l = (w0 == 0)   ? 0u : (uint32_t)rp[w0 - 1];
  uint32_t r = (w0 == 504) ? 0u : (uint32_t)rp[w0 + 8];
  v[0] = us2f(l);
  v[1] = us2f(cc.x & 0xffffu); v[2] = us2f(cc.x >> 16);
  v[3] = us2f(cc.y & 0xffffu); v[4] = us2f(cc.y >> 16);
  v[5] = us2f(cc.z & 0xffffu); v[6] = us2f(cc.z >> 16);
  v[7] = us2f(cc.w & 0xffffu); v[8] = us2f(cc.w >> 16);
  v[9] = us2f(r);
}

__device__ __forceinline__ void zero_row10(float* v){
  #pragma unroll
  for (int j = 0; j < 10; ++j) v[j] = 0.0f;
}

__device__ __forceinline__ void reduce2(float s, float q, float* __restrict__ partials){
  __shared__ float l2[2];
  int tid = threadIdx.x;
  if (tid < 2) l2[tid] = 0.0f;
  __syncthreads();
  #pragma unroll
  for (int off = 32; off >= 1; off >>= 1){
    s += __shfl_xor(s, off);
    q += __shfl_xor(q, off);
  }
  if ((tid & 63) == 0){ atomicAdd(&l2[0], s); atomicAdd(&l2[1], q); }
  __syncthreads();
  if (tid < 2) partials[blockIdx.x * 2 + tid] = l2[tid];
}

// ---------------------------------------------------------------------------
// A: conv stats of p only (first loop iteration input). grid 4096.
// ---------------------------------------------------------------------------
__global__ __launch_bounds__(256) void k_convstat(const bf16* __restrict__ d,
                                                  const float* __restrict__ dw,
                                                  float* __restrict__ P1){
  int bid = blockIdx.x;
  int plane = bid >> 7, rg = bid & 127;
  int f = plane & 15;
  int tid = threadIdx.x;
  int h  = (rg << 2) + (tid >> 6);
  int w0 = (tid & 63) << 3;
  const ushort* pl = (const ushort*)d + plane * HW;
  float wf[9];
  #pragma unroll
  for (int i = 0; i < 9; ++i) wf[i] = dw[f * 9 + i];
  float v[3][10];
  #pragma unroll
  for (int dy = 0; dy < 3; ++dy){
    int row = h + dy - 1;
    if ((unsigned)row < 512u) load_row10(pl + row * 512, w0, v[dy]);
    else zero_row10(v[dy]);
  }
  float s = 0.0f, q = 0.0f;
  #pragma unroll
  for (int k = 0; k < 8; ++k){
    float acc = 0.0f;
    #pragma unroll
    for (int dy = 0; dy < 3; ++dy)
      #pragma unroll
      for (int dx = 0; dx < 3; ++dx)
        acc = fmaf(wf[dy*3 + dx], v[dy][k + dx], acc);
    s += acc; q += acc * acc;
  }
  reduce2(s, q, P1);
}

// ---------------------------------------------------------------------------
// wave-parallel channel-f sum of a [32 planes][128 rg][2] partials buffer.
// Butterfly shuffle -> all lanes hold the sum; same order in every block/wave
// => bit-identical results everywhere. No barriers, no LDS.
// ---------------------------------------------------------------------------
__device__ __forceinline__ void chan_sum_wave(const float* __restrict__ P, int f, int lane,
                                              double& S, double& Q){
  S = 0.0; Q = 0.0;
  #pragma unroll
  for (int i = 0; i < 4; ++i){
    int e = lane + i * 64;                    // 0..255
    int blk = (((e >> 7) * 16 + f) << 7) + (e & 127);
    S += (double)P[blk * 2];
    Q += (double)P[blk * 2 + 1];
  }
  #pragma unroll
  for (int off = 32; off >= 1; off >>= 1){
    S += __shfl_xor(S, off);
    Q += __shfl_xor(Q, off);
  }
}

// ---------------------------------------------------------------------------
// FUSED loop kernel. grid 4096 (plane x 4-row group), 256 threads.
//   prologue: bnA params (sc,sh) for channel f from P1in (wave shuffle, 0 bar)
//   main:     conv(din)+bn+lrelu -> dout (global) + LDS strip; P2 stats of d
//   halo:     recompute rows h0-1 / h0+4 of d into LDS (bit-identical to the
//             neighboring blocks' stored values: same math, same rounding)
//   epilogue: conv(d) stats from LDS strip -> P1out (next iteration's stats)
// ---------------------------------------------------------------------------
__global__ __launch_bounds__(256) void k_bnfused(const bf16* __restrict__ din,
                                                 const float* __restrict__ dw,
                                                 const float* __restrict__ gd,
                                                 const float* __restrict__ bd,
                                                 const float* __restrict__ P1in,
                                                 bf16* __restrict__ dout,
                                                 float* __restrict__ P2out,
                                                 float* __restrict__ P1out){
  __shared__ ushort strip[6][512];
  __shared__ float acc4[4];
  int bid = blockIdx.x;
  int plane = bid >> 7, rg = bid & 127;
  int f = plane & 15;
  int tid = threadIdx.x;

  double S, Q;
  chan_sum_wave(P1in, f, tid & 63, S, Q);
  float sc, sh;
  {
    double m = S / 524288.0;
    double v = Q / 524288.0 - m * m;
    sc = gd[f] / sqrtf((float)v + EPSF);
    sh = bd[f] - (float)m * sc;
  }
  if (tid < 4) acc4[tid] = 0.0f;

  int h0 = rg << 2;
  int h  = h0 + (tid >> 6);
  int w0 = (tid & 63) << 3;
  const ushort* pl = (const ushort*)din + plane * HW;
  float wf[9];
  #pragma unroll
  for (int i = 0; i < 9; ++i) wf[i] = dw[f * 9 + i];

  // main rows
  float s2 = 0.0f, q2 = 0.0f;
  {
    float v[3][10];
    #pragma unroll
    for (int dy = 0; dy < 3; ++dy){
      int row = h + dy - 1;
      if ((unsigned)row < 512u) load_row10(pl + row * 512, w0, v[dy]);
      else zero_row10(v[dy]);
    }
    uint32_t ob[4];
    #pragma unroll
    for (int k = 0; k < 8; ++k){
      float acc = 0.0f;
      #pragma unroll
      for (int dy = 0; dy < 3; ++dy)
        #pragma unroll
        for (int dx = 0; dx < 3; ++dx)
          acc = fmaf(wf[dy*3 + dx], v[dy][k + dx], acc);
      float vv = lrelu(acc * sc + sh);
      uint32_t bits = (uint32_t)f2bu(vv);
      if ((k & 1) == 0) ob[k >> 1] = bits; else ob[k >> 1] |= bits << 16;
      s2 += vv; q2 += vv * vv;
    }
    uint4 ov; ov.x = ob[0]; ov.y = ob[1]; ov.z = ob[2]; ov.w = ob[3];
    *(uint4*)((ushort*)dout + plane * HW + h * 512 + w0) = ov;
    *(uint4*)&strip[1 + (tid >> 6)][w0] = ov;
  }

  // halo rows (threads 0..63 -> row h0-1, 64..127 -> row h0+4)
  if (tid < 128){
    int hh = (tid < 64) ? (h0 - 1) : (h0 + 4);
    int si = (tid < 64) ? 0 : 5;
    int wh0 = (tid & 63) << 3;
    uint4 hv; hv.x = 0; hv.y = 0; hv.z = 0; hv.w = 0;
    if ((unsigned)hh < 512u){
      float v[3][10];
      #pragma unroll
      for (int dy = 0; dy < 3; ++dy){
        int row = hh + dy - 1;
        if ((unsigned)row < 512u) load_row10(pl + row * 512, wh0, v[dy]);
        else zero_row10(v[dy]);
      }
      uint32_t hb[4];
      #pragma unroll
      for (int k = 0; k < 8; ++k){
        float acc = 0.0f;
        #pragma unroll
        for (int dy = 0; dy < 3; ++dy)
          #pragma unroll
          for (int dx = 0; dx < 3; ++dx)
            acc = fmaf(wf[dy*3 + dx], v[dy][k + dx], acc);
        float vv = lrelu(acc * sc + sh);
        uint32_t bits = (uint32_t)f2bu(vv);
        if ((k & 1) == 0) hb[k >> 1] = bits; else hb[k >> 1] |= bits << 16;
      }
      hv.x = hb[0]; hv.y = hb[1]; hv.z = hb[2]; hv.w = hb[3];
    }
    *(uint4*)&strip[si][wh0] = hv;
  }
  __syncthreads();

  // conv stats over the staged d strip
  float s1 = 0.0f, q1 = 0.0f;
  {
    int si = 1 + (tid >> 6);
    float v[3][10];
    #pragma unroll
    for (int dy = 0; dy < 3; ++dy)
      load_row10(&strip[si - 1 + dy][0], w0, v[dy]);
    #pragma unroll
    for (int k = 0; k < 8; ++k){
      float acc = 0.0f;
      #pragma unroll
      for (int dy = 0; dy < 3; ++dy)
        #pragma unroll
        for (int dx = 0; dx < 3; ++dx)
          acc = fmaf(wf[dy*3 + dx], v[dy][k + dx], acc);
      s1 += acc; q1 += acc * acc;
    }
  }

  // epilogue: reduce (s2,q2,s1,q1) across block, write partials
  #pragma unroll
  for (int off = 32; off >= 1; off >>= 1){
    s2 += __shfl_xor(s2, off);
    q2 += __shfl_xor(q2, off);
    s1 += __shfl_xor(s1, off);
    q1 += __shfl_xor(q1, off);
  }
  if ((tid & 63) == 0){
    atomicAdd(&acc4[0], s2); atomicAdd(&acc4[1], q2);
    atomicAdd(&acc4[2], s1); atomicAdd(&acc4[3], q1);
  }
  __syncthreads();
  if (tid < 2)      P2out[bid * 2 + tid]       = acc4[tid];
  else if (tid < 4) P1out[bid * 2 + (tid - 2)] = acc4[tid];
}

// ---------------------------------------------------------------------------
// k_fin_all: compute the 80 wdt/hgt param quadruples, ONE PAIR PER WAVE.
// grid 20 x 256 (4 waves/block) -> 80 waves, fully parallel.
// dparams[t*64 + {0,16,32,48} + f].
// ---------------------------------------------------------------------------
__global__ __launch_bounds__(256) void k_fin_all(const float* __restrict__ P2,
                                                 const float* __restrict__ ww,
                                                 const float* __restrict__ gw,
                                                 const float* __restrict__ bw,
                                                 const float* __restrict__ wh,
                                                 const float* __restrict__ gh,
                                                 const float* __restrict__ bh,
                                                 float* __restrict__ dparams){
  int tid = threadIdx.x;
  int wid = tid >> 6, lane = tid & 63;
  int pair = blockIdx.x * 4 + wid;              // 0..79
  int t = pair >> 4, f = pair & 15;
  double S, Q;
  chan_sum_wave(P2 + t * 8192, f, lane, S, Q);
  if (lane == 0){
    float m = (float)(S / 524288.0);
    float v = (float)(Q / 524288.0) - m * m;
    float sw = ww[f] * gw[f] / sqrtf(ww[f] * ww[f] * v + EPSF);
    float tw = bw[f] - m * sw;
    float s2 = wh[f] * gh[f] / sqrtf(wh[f] * wh[f] * v + EPSF);
    float t2 = bh[f] - m * s2;
    dparams[t * 64 + f]      = sw;
    dparams[t * 64 + 16 + f] = tw;
    dparams[t * 64 + 32 + f] = s2;
    dparams[t * 64 + 48 + f] = t2;
  }
}

// ---------------------------------------------------------------------------
// F: assemble out. 8 px/thread; ALL 12 uint4 loads issued up-front (memory-
// level parallelism), params read from dparams (precomputed by k_fin_all).
// ---------------------------------------------------------------------------
__device__ __forceinline__ void conv8(uint4 cc, float* v){
  v[0] = us2f(cc.x & 0xffffu); v[1] = us2f(cc.x >> 16);
  v[2] = us2f(cc.y & 0xffffu); v[3] = us2f(cc.y >> 16);
  v[4] = us2f(cc.z & 0xffffu); v[5] = us2f(cc.z >> 16);
  v[6] = us2f(cc.w & 0xffffu); v[7] = us2f(cc.w >> 16);
}

__global__ __launch_bounds__(256) void k_final(const bf16* __restrict__ p,
                                               const bf16* __restrict__ d1,
                                               const bf16* __restrict__ d2,
                                               const bf16* __restrict__ d3,
                                               const bf16* __restrict__ d4,
                                               const bf16* __restrict__ d5,
                                               const float* __restrict__ dparams,
                                               float* __restrict__ out){
  int tid = threadIdx.x;
  int f = blockIdx.x >> 7;                      // 128 blocks per f
  int gid = blockIdx.x * 256 + tid;             // 0 .. 524287
  int hw = (gid & 32767) << 3;
  int fo = f * HW + hw;
  int f1 = (16 + f) * HW + hw;

  // issue all 12 loads first
  uint4 rp0 = *(const uint4*)((const ushort*)p + fo);
  uint4 rp1 = *(const uint4*)((const ushort*)p + f1);
  uint4 r0a = *(const uint4*)((const ushort*)d1 + fo);
  uint4 r0b = *(const uint4*)((const ushort*)d1 + f1);
  uint4 r1a = *(const uint4*)((const ushort*)d2 + fo);
  uint4 r1b = *(const uint4*)((const ushort*)d2 + f1);
  uint4 r2a = *(const uint4*)((const ushort*)d3 + fo);
  uint4 r2b = *(const uint4*)((const ushort*)d3 + f1);
  uint4 r3a = *(const uint4*)((const ushort*)d4 + fo);
  uint4 r3b = *(const uint4*)((const ushort*)d4 + f1);
  uint4 r4a = *(const uint4*)((const ushort*)d5 + fo);
  uint4 r4b = *(const uint4*)((const ushort*)d5 + f1);

  float swA[5], twA[5], shA[5], thA[5];
  #pragma unroll
  for (int t = 0; t < 5; ++t){
    swA[t] = dparams[t * 64 + f];
    twA[t] = dparams[t * 64 + 16 + f];
    shA[t] = dparams[t * 64 + 32 + f];
    thA[t] = dparams[t * 64 + 48 + f];
  }

  float pf[8], pg[8];
  conv8(rp0, pf); conv8(rp1, pg);
  float a00[8], a01[8], a10[8], a11[8];
  #pragma unroll
  for (int k = 0; k < 8; ++k){ a00[k] = pf[k]; a01[k] = pg[k]; a10[k] = pf[k]; a11[k] = pg[k]; }

  uint4 ra[5] = { r0a, r1a, r2a, r3a, r4a };
  uint4 rb[5] = { r0b, r1b, r2b, r3b, r4b };
  #pragma unroll
  for (int t = 0; t < 5; ++t){
    float dv0[8], dv1[8];
    conv8(ra[t], dv0); conv8(rb[t], dv1);
    float sw = swA[t], tw = twA[t], sh = shA[t], th = thA[t];
    #pragma unroll
    for (int k = 0; k < 8; ++k){
      a00[k] += lrelu(fmaf(dv0[k], sw, tw));
      a01[k] += lrelu(fmaf(dv0[k], sh, th));
      a10[k] += lrelu(fmaf(dv1[k], sw, tw));
      a11[k] += lrelu(fmaf(dv1[k], sh, th));
    }
  }
  #pragma unroll
  for (int half = 0; half < 2; ++half){
    float4 v0 = { a00[half*4+0], a00[half*4+1], a00[half*4+2], a00[half*4+3] };
    float4 v1 = { a01[half*4+0], a01[half*4+1], a01[half*4+2], a01[half*4+3] };
    float4 v2 = { a10[half*4+0], a10[half*4+1], a10[half*4+2], a10[half*4+3] };
    float4 v3 = { a11[half*4+0], a11[half*4+1], a11[half*4+2], a11[half*4+3] };
    *(float4*)(out + f * HW + hw + half*4)        = v0;
    *(float4*)(out + (16 + f) * HW + hw + half*4) = v1;
    *(float4*)(out + (32 + f) * HW + hw + half*4) = v2;
    *(float4*)(out + (48 + f) * HW + hw + half*4) = v3;
  }
}

// ---------------------------------------------------------------------------
extern "C" void kernel_launch(void* const* d_in, const int* in_sizes, int n_in,
                              void* d_out, int out_size, void* d_ws, size_t ws_size,
                              hipStream_t stream){
  (void)in_sizes; (void)n_in; (void)out_size;
  const float* x   = (const float*)d_in[0];
  const float* w1  = (const float*)d_in[1];
  const float* b1  = (const float*)d_in[2];
  const float* g1  = (const float*)d_in[3];
  const float* be1 = (const float*)d_in[4];
  const float* w2  = (const float*)d_in[5];
  const float* b2  = (const float*)d_in[6];
  const float* g2  = (const float*)d_in[7];
  const float* be2 = (const float*)d_in[8];
  const float* dw  = (const float*)d_in[9];
  const float* gd  = (const float*)d_in[10];
  const float* bd  = (const float*)d_in[11];
  const float* ww  = (const float*)d_in[12];
  const float* gw  = (const float*)d_in[13];
  const float* bw  = (const float*)d_in[14];
  const float* wh  = (const float*)d_in[15];
  const float* gh  = (const float*)d_in[16];
  const float* bh  = (const float*)d_in[17];
  float* out = (float*)d_out;

  char* ws = (char*)d_ws;
  size_t off = 0;
  auto alloc = [&](size_t sz) -> void* {
    void* ptr = ws + off;
    off = (off + sz + 4095) & ~(size_t)4095;
    return ptr;
  };
  uint8_t* qpad  = (uint8_t*)alloc((size_t)6 * 522 * 528);
  uint8_t* xm    = (uint8_t*)alloc((size_t)6 * HW);
  bf16*    p     = (bf16*)   alloc((size_t)32 * HW * 2);
  bf16*    dbuf[5];
  for (int i = 0; i < 5; ++i) dbuf[i] = (bf16*)alloc((size_t)32 * HW * 2);
  float*   Pp1    = (float*)  alloc((size_t)512 * 32 * 4);
  float*   Pp2    = (float*)  alloc((size_t)512 * 32 * 4);
  float*   P1a    = (float*)  alloc((size_t)4096 * 2 * 4);
  float*   P1b    = (float*)  alloc((size_t)4096 * 2 * 4);
  float*   P2     = (float*)  alloc((size_t)5 * 4096 * 2 * 4);
  float*   dparams= (float*)  alloc(4096);
  if (ws_size < off) return;   // workspace too small: fail visibly (untouched out)

  k_quant_pad<<<dim3((6*522*522 + 255)/256), dim3(256), 0, stream>>>(x, qpad);
  k_mode     <<<dim3(768), dim3(256), 0, stream>>>(qpad, xm);
  k_stats1   <<<dim3(512), dim3(256), 0, stream>>>(xm, w1, b1, Pp1);
  k_stats2   <<<dim3(512), dim3(256), 0, stream>>>(xm, w1, b1, w2, b2,
                                                   Pp1, g1, be1, Pp2);
  k_prep     <<<dim3(512), dim3(256), 0, stream>>>(xm, w1, b1, w2, b2,
                                                   Pp1, g1, be1, Pp2, g2, be2, p);
  k_convstat <<<dim3(4096), dim3(256), 0, stream>>>(p, dw, P1a);

  const bf16* dcur = p;
  float* Pin = P1a; float* Pout = P1b;
  for (int t = 0; t < 5; ++t){
    k_bnfused<<<dim3(4096), dim3(256), 0, stream>>>(dcur, dw, gd, bd, Pin,
                                                    dbuf[t], P2 + t * 8192, Pout);
    dcur = dbuf[t];
    float* tmp = Pin; Pin = Pout; Pout = tmp;
  }
  k_fin_all<<<dim3(20), dim3(256), 0, stream>>>(P2, ww, gw, bw, wh, gh, bh, dparams);
  k_final<<<dim3(2048), dim3(256), 0, stream>>>(p, dbuf[0], dbuf[1], dbuf[2],
                                                dbuf[3], dbuf[4], dparams, out);
}

// Round 10
// 223.599 us; speedup vs baseline: 1.2281x; 1.2281x over previous
//
#include <hip/hip_runtime.h>
#include <hip/hip_bf16.h>
#include <stdint.h>
#include <stddef.h>

#define HW 262144          // 512*512
#define EPSF 1e-5f

typedef __hip_bfloat16 bf16;

__device__ __forceinline__ float us2f(uint32_t u){
  union { uint32_t i; float f; } c; c.i = u << 16; return c.f;
}
__device__ __forceinline__ ushort f2bu(float v){
  union { bf16 h; ushort u; } c; c.h = __float2bfloat16(v); return c.u;
}
__device__ __forceinline__ float lrelu(float v){ return v > 0.0f ? v : 0.01f * v; }
__device__ __forceinline__ uint32_t umax2(uint32_t a, uint32_t b){ return a > b ? a : b; }

// ---------------------------------------------------------------------------
// K0a: quantize x to level k = rint(x*255/16), materialize reflect-padded u8
// plane [6][522 rows][pitch 528]
// ---------------------------------------------------------------------------
__global__ __launch_bounds__(256) void k_quant_pad(const float* __restrict__ x,
                                                   uint8_t* __restrict__ qpad){
  int idx = blockIdx.x * 256 + threadIdx.x;
  if (idx >= 6 * 522 * 522) return;
  int pw = idx % 522; int t = idx / 522; int ph = t % 522; int img = t / 522;
  int h = ph - 5; h = h < 0 ? -h : h; if (h > 511) h = 1022 - h;
  int w = pw - 5; w = w < 0 ? -w : w; if (w > 511) w = 1022 - w;
  float v = x[img * HW + h * 512 + w];
  int k = (int)rintf((v * 255.0f) / 16.0f);   // round-half-even, matches jnp.round
  qpad[img * (522 * 528) + ph * 528 + pw] = (uint8_t)k;
}

// ---------------------------------------------------------------------------
// K0b: 11x11 mode filter (LDS tile, rolled loops to avoid VGPR spill — r4/r5).
// ---------------------------------------------------------------------------
__global__ __launch_bounds__(256) void k_mode(const uint8_t* __restrict__ qpad,
                                              uint8_t* __restrict__ xm){
  __shared__ uint8_t tile[14 * 528];          // 7392 B
  int tid = threadIdx.x;
  int img = blockIdx.x >> 7;
  int h0  = (blockIdx.x & 127) << 2;          // first output row of block
  {
    const uint4* g4 = (const uint4*)(qpad + img * (522 * 528) + h0 * 528);
    uint4* t4 = (uint4*)tile;
    t4[tid] = g4[tid];                        // 0..255
    if (tid < 206) t4[tid + 256] = g4[tid + 256];   // 256..461 (462 total)
  }
  __syncthreads();
  int r4 = tid >> 6;                          // row within block 0..3
  int w0 = (tid & 63) << 3;                   // 0..504
  const uint8_t* base = tile + r4 * 528 + w0;
  uint32_t c0 = 0, c1 = 0, c2 = 0, c3 = 0, c4 = 0;
#define HINC(q) { uint32_t inc_ = 1u << (((q) & 3u) << 3); uint32_t rr_ = (q) >> 2; \
    c0 += (rr_==0u)?inc_:0u; c1 += (rr_==1u)?inc_:0u; c2 += (rr_==2u)?inc_:0u; \
    c3 += (rr_==3u)?inc_:0u; c4 += (rr_==4u)?inc_:0u; }
#define HDEC(q) { uint32_t inc_ = 1u << (((q) & 3u) << 3); uint32_t rr_ = (q) >> 2; \
    c0 -= (rr_==0u)?inc_:0u; c1 -= (rr_==1u)?inc_:0u; c2 -= (rr_==2u)?inc_:0u; \
    c3 -= (rr_==3u)?inc_:0u; c4 -= (rr_==4u)?inc_:0u; }
  #pragma unroll 1
  for (int r = 0; r < 11; ++r){
    const uint8_t* row = base + r * 528;
    #pragma unroll
    for (int j = 0; j < 11; ++j){ uint32_t q = row[j]; HINC(q); }
  }
  uint64_t packed = 0;
  #pragma unroll 1
  for (int s = 0; s < 8; ++s){
    // key(l) = (cnt<<5) | (16-l); max key -> max cnt, tie -> smallest level
#define KEY(reg, sh, l) (((((reg) >> (sh)) & 0xffu) << 5) | (16u - (uint32_t)(l)))
    uint32_t m0 = umax2(umax2(KEY(c0,0,0),  KEY(c0,8,1)),  umax2(KEY(c0,16,2),  KEY(c0,24,3)));
    uint32_t m1 = umax2(umax2(KEY(c1,0,4),  KEY(c1,8,5)),  umax2(KEY(c1,16,6),  KEY(c1,24,7)));
    uint32_t m2 = umax2(umax2(KEY(c2,0,8),  KEY(c2,8,9)),  umax2(KEY(c2,16,10), KEY(c2,24,11)));
    uint32_t m3 = umax2(umax2(KEY(c3,0,12), KEY(c3,8,13)), umax2(KEY(c3,16,14), KEY(c3,24,15)));
    uint32_t m  = umax2(umax2(umax2(m0, m1), umax2(m2, m3)), KEY(c4,0,16));
#undef KEY
    uint32_t lvl = 16u - (m & 31u);
    packed |= ((uint64_t)lvl) << (8 * s);
    if (s < 7){
      #pragma unroll
      for (int r = 0; r < 11; ++r){
        uint32_t qo = base[r * 528 + s];      HDEC(qo);
        uint32_t qn = base[r * 528 + s + 11]; HINC(qn);
      }
    }
  }
#undef HINC
#undef HDEC
  *(uint64_t*)(xm + img * HW + (h0 + r4) * 512 + w0) = packed;
}

// ---------------------------------------------------------------------------
// block reduction of per-thread su[16]/sq[16] -> partials[block][32]
// ---------------------------------------------------------------------------
__device__ __forceinline__ void reduce16(float* su, float* sq, float* __restrict__ partials){
  __shared__ float lsum[32];
  int tid = threadIdx.x;
  if (tid < 32) lsum[tid] = 0.0f;
  __syncthreads();
  #pragma unroll
  for (int o = 0; o < 16; ++o){
    float s = su[o], q = sq[o];
    #pragma unroll
    for (int off = 32; off >= 1; off >>= 1){
      s += __shfl_xor(s, off);
      q += __shfl_xor(q, off);
    }
    if ((tid & 63) == 0){ atomicAdd(&lsum[o], s); atomicAdd(&lsum[16 + o], q); }
  }
  __syncthreads();
  if (tid < 32) partials[blockIdx.x * 32 + tid] = lsum[tid];
}

// ---------------------------------------------------------------------------
// K1: stats of p1 = conv1x1(xm). 4 px/thread. grid 512 x 256.
// ---------------------------------------------------------------------------
__global__ __launch_bounds__(256) void k_stats1(const uint8_t* __restrict__ xm,
                                                const float* __restrict__ w1,
                                                const float* __restrict__ b1,
                                                float* __restrict__ partials){
  int t0 = (blockIdx.x * 256 + threadIdx.x) << 2;
  int b = t0 >> 18, hw = t0 & (HW - 1);
  uint32_t q0 = *(const uint32_t*)(xm + (b * 3 + 0) * HW + hw);
  uint32_t q1 = *(const uint32_t*)(xm + (b * 3 + 1) * HW + hw);
  uint32_t q2 = *(const uint32_t*)(xm + (b * 3 + 2) * HW + hw);
  float su[16], sq[16];
  #pragma unroll
  for (int o = 0; o < 16; ++o){ su[o] = 0.0f; sq[o] = 0.0f; }
  #pragma unroll
  for (int px = 0; px < 4; ++px){
    float x0 = (float)((q0 >> (8 * px)) & 0xffu) * 0.0625f;
    float x1 = (float)((q1 >> (8 * px)) & 0xffu) * 0.0625f;
    float x2 = (float)((q2 >> (8 * px)) & 0xffu) * 0.0625f;
    #pragma unroll
    for (int o = 0; o < 16; ++o){
      float v = b1[o] + w1[o*3]*x0 + w1[o*3+1]*x1 + w1[o*3+2]*x2;
      su[o] += v; sq[o] += v * v;
    }
  }
  reduce16(su, sq, partials);
}

// ---------------------------------------------------------------------------
// K2: recompute p1, bn1+lrelu, p2 = conv1x1, stats of p2. 4 px/thread.
// ---------------------------------------------------------------------------
__global__ __launch_bounds__(256) void k_stats2(const uint8_t* __restrict__ xm,
                                                const float* __restrict__ w1,
                                                const float* __restrict__ b1,
                                                const float* __restrict__ w2,
                                                const float* __restrict__ b2,
                                                const float* __restrict__ params,
                                                float* __restrict__ partials){
  int t0 = (blockIdx.x * 256 + threadIdx.x) << 2;
  int b = t0 >> 18, hw = t0 & (HW - 1);
  uint32_t q0 = *(const uint32_t*)(xm + (b * 3 + 0) * HW + hw);
  uint32_t q1 = *(const uint32_t*)(xm + (b * 3 + 1) * HW + hw);
  uint32_t q2 = *(const uint32_t*)(xm + (b * 3 + 2) * HW + hw);
  float tv[4][16];
  #pragma unroll
  for (int px = 0; px < 4; ++px){
    float x0 = (float)((q0 >> (8 * px)) & 0xffu) * 0.0625f;
    float x1 = (float)((q1 >> (8 * px)) & 0xffu) * 0.0625f;
    float x2 = (float)((q2 >> (8 * px)) & 0xffu) * 0.0625f;
    #pragma unroll
    for (int o = 0; o < 16; ++o){
      float v = b1[o] + w1[o*3]*x0 + w1[o*3+1]*x1 + w1[o*3+2]*x2;
      tv[px][o] = lrelu(v * params[o] + params[16 + o]);
    }
  }
  float su[16], sq[16];
  #pragma unroll
  for (int o = 0; o < 16; ++o){ su[o] = 0.0f; sq[o] = 0.0f; }
  #pragma unroll
  for (int o = 0; o < 16; ++o){
    #pragma unroll
    for (int px = 0; px < 4; ++px){
      float acc = b2[o];
      #pragma unroll
      for (int c = 0; c < 16; ++c) acc = fmaf(w2[o*16 + c], tv[px][c], acc);
      su[o] += acc; sq[o] += acc * acc;
    }
  }
  reduce16(su, sq, partials);
}

// ---------------------------------------------------------------------------
// K3: recompute p2, bn2+lrelu, write p (bf16). 4 px/thread.
// ---------------------------------------------------------------------------
__global__ __launch_bounds__(256) void k_prep(const uint8_t* __restrict__ xm,
                                              const float* __restrict__ w1,
                                              const float* __restrict__ b1,
                                              const float* __restrict__ w2,
                                              const float* __restrict__ b2,
                                              const float* __restrict__ params,
                                              bf16* __restrict__ p){
  int t0 = (blockIdx.x * 256 + threadIdx.x) << 2;
  int b = t0 >> 18, hw = t0 & (HW - 1);
  uint32_t q0 = *(const uint32_t*)(xm + (b * 3 + 0) * HW + hw);
  uint32_t q1 = *(const uint32_t*)(xm + (b * 3 + 1) * HW + hw);
  uint32_t q2 = *(const uint32_t*)(xm + (b * 3 + 2) * HW + hw);
  float tv[4][16];
  #pragma unroll
  for (int px = 0; px < 4; ++px){
    float x0 = (float)((q0 >> (8 * px)) & 0xffu) * 0.0625f;
    float x1 = (float)((q1 >> (8 * px)) & 0xffu) * 0.0625f;
    float x2 = (float)((q2 >> (8 * px)) & 0xffu) * 0.0625f;
    #pragma unroll
    for (int o = 0; o < 16; ++o){
      float v = b1[o] + w1[o*3]*x0 + w1[o*3+1]*x1 + w1[o*3+2]*x2;
      tv[px][o] = lrelu(v * params[o] + params[16 + o]);
    }
  }
  #pragma unroll
  for (int o = 0; o < 16; ++o){
    uint32_t w01 = 0, w23 = 0;
    #pragma unroll
    for (int px = 0; px < 4; ++px){
      float acc = b2[o];
      #pragma unroll
      for (int c = 0; c < 16; ++c) acc = fmaf(w2[o*16 + c], tv[px][c], acc);
      float v = lrelu(acc * params[32 + o] + params[48 + o]);
      uint32_t bits = (uint32_t)f2bu(v);
      if (px == 0) w01 = bits;
      else if (px == 1) w01 |= bits << 16;
      else if (px == 2) w23 = bits;
      else w23 |= bits << 16;
    }
    uint2 ov; ov.x = w01; ov.y = w23;
    *(uint2*)((ushort*)p + (b * 16 + o) * HW + hw) = ov;
  }
}

// ---------------------------------------------------------------------------
// row loader for depthwise conv: 10 values (cols w0-1 .. w0+8), zero-padded.
// ---------------------------------------------------------------------------
__device__ __forceinline__ void load_row10(const ushort* __restrict__ rp, int w0, float* v){
  uint4 cc = *(const uint4*)(rp + w0);
  uint32_t l = (w0 == 0)   ? 0u : (uint32_t)rp[w0 - 1];
  uint32_t r = (w0 == 504) ? 0u : (uint32_t)rp[w0 + 8];
  v[0] = us2f(l);
  v[1] = us2f(cc.x & 0xffffu); v[2] = us2f(cc.x >> 16);
  v[3] = us2f(cc.y & 0xffffu); v[4] = us2f(cc.y >> 16);
  v[5] = us2f(cc.z & 0xffffu); v[6] = us2f(cc.z >> 16);
  v[7] = us2f(cc.w & 0xffffu); v[8] = us2f(cc.w >> 16);
  v[9] = us2f(r);
}

__device__ __forceinline__ void zero_row10(float* v){
  #pragma unroll
  for (int j = 0; j < 10; ++j) v[j] = 0.0f;
}

__device__ __forceinline__ void reduce2(float s, float q, float* __restrict__ partials){
  __shared__ float l2[2];
  int tid = threadIdx.x;
  if (tid < 2) l2[tid] = 0.0f;
  __syncthreads();
  #pragma unroll
  for (int off = 32; off >= 1; off >>= 1){
    s += __shfl_xor(s, off);
    q += __shfl_xor(q, off);
  }
  if ((tid & 63) == 0){ atomicAdd(&l2[0], s); atomicAdd(&l2[1], q); }
  __syncthreads();
  if (tid < 2) partials[blockIdx.x * 2 + tid] = l2[tid];
}

// ---------------------------------------------------------------------------
// A: conv stats of p + write c0 = conv(p) (bf16). grid 4096.
// ---------------------------------------------------------------------------
__global__ __launch_bounds__(256) void k_convstat(const bf16* __restrict__ d,
                                                  const float* __restrict__ dw,
                                                  float* __restrict__ P1,
                                                  bf16* __restrict__ cout){
  int bid = blockIdx.x;
  int plane = bid >> 7, rg = bid & 127;
  int f = plane & 15;
  int tid = threadIdx.x;
  int h  = (rg << 2) + (tid >> 6);
  int w0 = (tid & 63) << 3;
  const ushort* pl = (const ushort*)d + plane * HW;
  float wf[9];
  #pragma unroll
  for (int i = 0; i < 9; ++i) wf[i] = dw[f * 9 + i];
  float v[3][10];
  #pragma unroll
  for (int dy = 0; dy < 3; ++dy){
    int row = h + dy - 1;
    if ((unsigned)row < 512u) load_row10(pl + row * 512, w0, v[dy]);
    else zero_row10(v[dy]);
  }
  float s = 0.0f, q = 0.0f;
  uint32_t cb[4];
  #pragma unroll
  for (int k = 0; k < 8; ++k){
    float acc = 0.0f;
    #pragma unroll
    for (int dy = 0; dy < 3; ++dy)
      #pragma unroll
      for (int dx = 0; dx < 3; ++dx)
        acc = fmaf(wf[dy*3 + dx], v[dy][k + dx], acc);
    s += acc; q += acc * acc;
    uint32_t bits = (uint32_t)f2bu(acc);
    if ((k & 1) == 0) cb[k >> 1] = bits; else cb[k >> 1] |= bits << 16;
  }
  uint4 cv; cv.x = cb[0]; cv.y = cb[1]; cv.z = cb[2]; cv.w = cb[3];
  *(uint4*)((ushort*)cout + plane * HW + h * 512 + w0) = cv;
  reduce2(s, q, P1);
}

// ---------------------------------------------------------------------------
// wave-parallel channel-f sum of a [32 planes][128 rg][2] partials buffer.
// ---------------------------------------------------------------------------
__device__ __forceinline__ void chan_sum_wave(const float* __restrict__ P, int f, int lane,
                                              double& S, double& Q){
  S = 0.0; Q = 0.0;
  #pragma unroll
  for (int i = 0; i < 4; ++i){
    int e = lane + i * 64;                    // 0..255
    int blk = (((e >> 7) * 16 + f) << 7) + (e & 127);
    S += (double)P[blk * 2];
    Q += (double)P[blk * 2 + 1];
  }
  #pragma unroll
  for (int off = 32; off >= 1; off >>= 1){
    S += __shfl_xor(S, off);
    Q += __shfl_xor(Q, off);
  }
}

// ---------------------------------------------------------------------------
// FUSED loop kernel (c-carry form). grid 4096, 256 threads.
//   prologue: bnA params (sc,sh) for channel f from P1in (wave shuffle)
//   main:     d = lrelu(cin*sc+sh)  (1 uint4 load!) -> dout + LDS strip; P2
//   halo:     same for rows h0-1 / h0+4 (1 load each, bit-identical)
//   strip:    c_next = conv(d strip) -> cout (bf16) + P1out stats
// ---------------------------------------------------------------------------
__global__ __launch_bounds__(256) void k_bnfused(const bf16* __restrict__ cin,
                                                 const float* __restrict__ dw,
                                                 const float* __restrict__ gd,
                                                 const float* __restrict__ bd,
                                                 const float* __restrict__ P1in,
                                                 bf16* __restrict__ dout,
                                                 bf16* __restrict__ cout,
                                                 float* __restrict__ P2out,
                                                 float* __restrict__ P1out,
                                                 int write_c){
  __shared__ ushort strip[6][512];
  __shared__ float acc4[4];
  int bid = blockIdx.x;
  int plane = bid >> 7, rg = bid & 127;
  int f = plane & 15;
  int tid = threadIdx.x;

  double S, Q;
  chan_sum_wave(P1in, f, tid & 63, S, Q);
  float sc, sh;
  {
    double m = S / 524288.0;
    double v = Q / 524288.0 - m * m;
    sc = gd[f] / sqrtf((float)v + EPSF);
    sh = bd[f] - (float)m * sc;
  }
  if (tid < 4) acc4[tid] = 0.0f;

  int h0 = rg << 2;
  int h  = h0 + (tid >> 6);
  int w0 = (tid & 63) << 3;
  const ushort* cpl = (const ushort*)cin + plane * HW;

  // main rows: d = lrelu(c*sc+sh)
  float s2 = 0.0f, q2 = 0.0f;
  {
    uint4 cv = *(const uint4*)(cpl + h * 512 + w0);
    float cf[8];
    cf[0] = us2f(cv.x & 0xffffu); cf[1] = us2f(cv.x >> 16);
    cf[2] = us2f(cv.y & 0xffffu); cf[3] = us2f(cv.y >> 16);
    cf[4] = us2f(cv.z & 0xffffu); cf[5] = us2f(cv.z >> 16);
    cf[6] = us2f(cv.w & 0xffffu); cf[7] = us2f(cv.w >> 16);
    uint32_t ob[4];
    #pragma unroll
    for (int k = 0; k < 8; ++k){
      float vv = lrelu(fmaf(cf[k], sc, sh));
      uint32_t bits = (uint32_t)f2bu(vv);
      if ((k & 1) == 0) ob[k >> 1] = bits; else ob[k >> 1] |= bits << 16;
      s2 += vv; q2 += vv * vv;
    }
    uint4 ov; ov.x = ob[0]; ov.y = ob[1]; ov.z = ob[2]; ov.w = ob[3];
    *(uint4*)((ushort*)dout + plane * HW + h * 512 + w0) = ov;
    *(uint4*)&strip[1 + (tid >> 6)][w0] = ov;
  }

  // halo rows (threads 0..63 -> row h0-1, 64..127 -> row h0+4)
  if (tid < 128){
    int hh = (tid < 64) ? (h0 - 1) : (h0 + 4);
    int si = (tid < 64) ? 0 : 5;
    int wh0 = (tid & 63) << 3;
    uint4 hv; hv.x = 0; hv.y = 0; hv.z = 0; hv.w = 0;
    if ((unsigned)hh < 512u){
      uint4 cv = *(const uint4*)(cpl + hh * 512 + wh0);
      float cf[8];
      cf[0] = us2f(cv.x & 0xffffu); cf[1] = us2f(cv.x >> 16);
      cf[2] = us2f(cv.y & 0xffffu); cf[3] = us2f(cv.y >> 16);
      cf[4] = us2f(cv.z & 0xffffu); cf[5] = us2f(cv.z >> 16);
      cf[6] = us2f(cv.w & 0xffffu); cf[7] = us2f(cv.w >> 16);
      uint32_t hb[4];
      #pragma unroll
      for (int k = 0; k < 8; ++k){
        float vv = lrelu(fmaf(cf[k], sc, sh));
        uint32_t bits = (uint32_t)f2bu(vv);
        if ((k & 1) == 0) hb[k >> 1] = bits; else hb[k >> 1] |= bits << 16;
      }
      hv.x = hb[0]; hv.y = hb[1]; hv.z = hb[2]; hv.w = hb[3];
    }
    *(uint4*)&strip[si][wh0] = hv;
  }
  __syncthreads();

  // strip conv: c_next = conv(d); stats + optional bf16 store
  float wf[9];
  #pragma unroll
  for (int i = 0; i < 9; ++i) wf[i] = dw[f * 9 + i];
  float s1 = 0.0f, q1 = 0.0f;
  {
    int si = 1 + (tid >> 6);
    float v[3][10];
    #pragma unroll
    for (int dy = 0; dy < 3; ++dy)
      load_row10(&strip[si - 1 + dy][0], w0, v[dy]);
    uint32_t cb[4];
    #pragma unroll
    for (int k = 0; k < 8; ++k){
      float acc = 0.0f;
      #pragma unroll
      for (int dy = 0; dy < 3; ++dy)
        #pragma unroll
        for (int dx = 0; dx < 3; ++dx)
          acc = fmaf(wf[dy*3 + dx], v[dy][k + dx], acc);
      s1 += acc; q1 += acc * acc;
      uint32_t bits = (uint32_t)f2bu(acc);
      if ((k & 1) == 0) cb[k >> 1] = bits; else cb[k >> 1] |= bits << 16;
    }
    if (write_c){
      uint4 cv2; cv2.x = cb[0]; cv2.y = cb[1]; cv2.z = cb[2]; cv2.w = cb[3];
      *(uint4*)((ushort*)cout + plane * HW + h * 512 + w0) = cv2;
    }
  }

  // epilogue: reduce (s2,q2,s1,q1) across block, write partials
  #pragma unroll
  for (int off = 32; off >= 1; off >>= 1){
    s2 += __shfl_xor(s2, off);
    q2 += __shfl_xor(q2, off);
    s1 += __shfl_xor(s1, off);
    q1 += __shfl_xor(q1, off);
  }
  if ((tid & 63) == 0){
    atomicAdd(&acc4[0], s2); atomicAdd(&acc4[1], q2);
    atomicAdd(&acc4[2], s1); atomicAdd(&acc4[3], q1);
  }
  __syncthreads();
  if (tid < 2)      P2out[bid * 2 + tid]       = acc4[tid];
  else if (tid < 4) P1out[bid * 2 + (tid - 2)] = acc4[tid];
}

// ---------------------------------------------------------------------------
// finalize: prepare-stage BN (512-block x 32 partials layout), grid 1
// ---------------------------------------------------------------------------
__global__ __launch_bounds__(256) void k_fin_prep(const float* __restrict__ partials,
                                                  const float* __restrict__ g,
                                                  const float* __restrict__ bb,
                                                  float* __restrict__ params,
                                                  int offS, int offT){
  int tid = threadIdx.x;
  int o = tid & 15, c = tid >> 4;
  double S = 0.0, Q = 0.0;
  for (int i = c * 32; i < (c + 1) * 32; ++i){
    S += (double)partials[i * 32 + o];
    Q += (double)partials[i * 32 + 16 + o];
  }
  __shared__ double lS[256], lQ[256];
  lS[tid] = S; lQ[tid] = Q; __syncthreads();
  for (int st = 8; st >= 1; st >>= 1){
    if (c < st){ lS[tid] += lS[tid + st * 16]; lQ[tid] += lQ[tid + st * 16]; }
    __syncthreads();
  }
  if (tid < 16){
    double m = lS[tid] / 524288.0;
    double v = lQ[tid] / 524288.0 - m * m;
    float sc = g[tid] / sqrtf((float)v + EPSF);
    params[offS + tid] = sc;
    params[offT + tid] = bb[tid] - (float)m * sc;
  }
}

// ---------------------------------------------------------------------------
// k_fin_all: 80 wdt/hgt param quadruples, one (t,f) pair per wave. grid 20.
// ---------------------------------------------------------------------------
__global__ __launch_bounds__(256) void k_fin_all(const float* __restrict__ P2,
                                                 const float* __restrict__ ww,
                                                 const float* __restrict__ gw,
                                                 const float* __restrict__ bw,
                                                 const float* __restrict__ wh,
                                                 const float* __restrict__ gh,
                                                 const float* __restrict__ bh,
                                                 float* __restrict__ dparams){
  int tid = threadIdx.x;
  int wid = tid >> 6, lane = tid & 63;
  int pair = blockIdx.x * 4 + wid;              // 0..79
  int t = pair >> 4, f = pair & 15;
  double S, Q;
  chan_sum_wave(P2 + t * 8192, f, lane, S, Q);
  if (lane == 0){
    float m = (float)(S / 524288.0);
    float v = (float)(Q / 524288.0) - m * m;
    float sw = ww[f] * gw[f] / sqrtf(ww[f] * ww[f] * v + EPSF);
    float tw = bw[f] - m * sw;
    float s2 = wh[f] * gh[f] / sqrtf(wh[f] * wh[f] * v + EPSF);
    float t2 = bh[f] - m * s2;
    dparams[t * 64 + f]      = sw;
    dparams[t * 64 + 16 + f] = tw;
    dparams[t * 64 + 32 + f] = s2;
    dparams[t * 64 + 48 + f] = t2;
  }
}

// ---------------------------------------------------------------------------
// F: assemble out. 8 px/thread; all 12 uint4 loads up-front.
// ---------------------------------------------------------------------------
__device__ __forceinline__ void conv8(uint4 cc, float* v){
  v[0] = us2f(cc.x & 0xffffu); v[1] = us2f(cc.x >> 16);
  v[2] = us2f(cc.y & 0xffffu); v[3] = us2f(cc.y >> 16);
  v[4] = us2f(cc.z & 0xffffu); v[5] = us2f(cc.z >> 16);
  v[6] = us2f(cc.w & 0xffffu); v[7] = us2f(cc.w >> 16);
}

__global__ __launch_bounds__(256) void k_final(const bf16* __restrict__ p,
                                               const bf16* __restrict__ d1,
                                               const bf16* __restrict__ d2,
                                               const bf16* __restrict__ d3,
                                               const bf16* __restrict__ d4,
                                               const bf16* __restrict__ d5,
                                               const float* __restrict__ dparams,
                                               float* __restrict__ out){
  int tid = threadIdx.x;
  int f = blockIdx.x >> 7;                      // 128 blocks per f
  int gid = blockIdx.x * 256 + tid;             // 0 .. 524287
  int hw = (gid & 32767) << 3;
  int fo = f * HW + hw;
  int f1 = (16 + f) * HW + hw;

  uint4 rp0 = *(const uint4*)((const ushort*)p + fo);
  uint4 rp1 = *(const uint4*)((const ushort*)p + f1);
  uint4 r0a = *(const uint4*)((const ushort*)d1 + fo);
  uint4 r0b = *(const uint4*)((const ushort*)d1 + f1);
  uint4 r1a = *(const uint4*)((const ushort*)d2 + fo);
  uint4 r1b = *(const uint4*)((const ushort*)d2 + f1);
  uint4 r2a = *(const uint4*)((const ushort*)d3 + fo);
  uint4 r2b = *(const uint4*)((const ushort*)d3 + f1);
  uint4 r3a = *(const uint4*)((const ushort*)d4 + fo);
  uint4 r3b = *(const uint4*)((const ushort*)d4 + f1);
  uint4 r4a = *(const uint4*)((const ushort*)d5 + fo);
  uint4 r4b = *(const uint4*)((const ushort*)d5 + f1);

  float swA[5], twA[5], shA[5], thA[5];
  #pragma unroll
  for (int t = 0; t < 5; ++t){
    swA[t] = dparams[t * 64 + f];
    twA[t] = dparams[t * 64 + 16 + f];
    shA[t] = dparams[t * 64 + 32 + f];
    thA[t] = dparams[t * 64 + 48 + f];
  }

  float pf[8], pg[8];
  conv8(rp0, pf); conv8(rp1, pg);
  float a00[8], a01[8], a10[8], a11[8];
  #pragma unroll
  for (int k = 0; k < 8; ++k){ a00[k] = pf[k]; a01[k] = pg[k]; a10[k] = pf[k]; a11[k] = pg[k]; }

  uint4 ra[5] = { r0a, r1a, r2a, r3a, r4a };
  uint4 rb[5] = { r0b, r1b, r2b, r3b, r4b };
  #pragma unroll
  for (int t = 0; t < 5; ++t){
    float dv0[8], dv1[8];
    conv8(ra[t], dv0); conv8(rb[t], dv1);
    float sw = swA[t], tw = twA[t], sh = shA[t], th = thA[t];
    #pragma unroll
    for (int k = 0; k < 8; ++k){
      a00[k] += lrelu(fmaf(dv0[k], sw, tw));
      a01[k] += lrelu(fmaf(dv0[k], sh, th));
      a10[k] += lrelu(fmaf(dv1[k], sw, tw));
      a11[k] += lrelu(fmaf(dv1[k], sh, th));
    }
  }
  #pragma unroll
  for (int half = 0; half < 2; ++half){
    float4 v0 = { a00[half*4+0], a00[half*4+1], a00[half*4+2], a00[half*4+3] };
    float4 v1 = { a01[half*4+0], a01[half*4+1], a01[half*4+2], a01[half*4+3] };
    float4 v2 = { a10[half*4+0], a10[half*4+1], a10[half*4+2], a10[half*4+3] };
    float4 v3 = { a11[half*4+0], a11[half*4+1], a11[half*4+2], a11[half*4+3] };
    *(float4*)(out + f * HW + hw + half*4)        = v0;
    *(float4*)(out + (16 + f) * HW + hw + half*4) = v1;
    *(float4*)(out + (32 + f) * HW + hw + half*4) = v2;
    *(float4*)(out + (48 + f) * HW + hw + half*4) = v3;
  }
}

// ---------------------------------------------------------------------------
extern "C" void kernel_launch(void* const* d_in, const int* in_sizes, int n_in,
                              void* d_out, int out_size, void* d_ws, size_t ws_size,
                              hipStream_t stream){
  (void)in_sizes; (void)n_in; (void)out_size;
  const float* x   = (const float*)d_in[0];
  const float* w1  = (const float*)d_in[1];
  const float* b1  = (const float*)d_in[2];
  const float* g1  = (const float*)d_in[3];
  const float* be1 = (const float*)d_in[4];
  const float* w2  = (const float*)d_in[5];
  const float* b2  = (const float*)d_in[6];
  const float* g2  = (const float*)d_in[7];
  const float* be2 = (const float*)d_in[8];
  const float* dw  = (const float*)d_in[9];
  const float* gd  = (const float*)d_in[10];
  const float* bd  = (const float*)d_in[11];
  const float* ww  = (const float*)d_in[12];
  const float* gw  = (const float*)d_in[13];
  const float* bw  = (const float*)d_in[14];
  const float* wh  = (const float*)d_in[15];
  const float* gh  = (const float*)d_in[16];
  const float* bh  = (const float*)d_in[17];
  float* out = (float*)d_out;

  char* ws = (char*)d_ws;
  size_t off = 0;
  auto alloc = [&](size_t sz) -> void* {
    void* ptr = ws + off;
    off = (off + sz + 4095) & ~(size_t)4095;
    return ptr;
  };
  uint8_t* qpad  = (uint8_t*)alloc((size_t)6 * 522 * 528);
  uint8_t* xm    = (uint8_t*)alloc((size_t)6 * HW);
  bf16*    p     = (bf16*)   alloc((size_t)32 * HW * 2);
  bf16*    dbuf[5];
  for (int i = 0; i < 5; ++i) dbuf[i] = (bf16*)alloc((size_t)32 * HW * 2);
  float*   Pp     = (float*)  alloc((size_t)512 * 32 * 4);
  float*   P1a    = (float*)  alloc((size_t)4096 * 2 * 4);
  float*   P1b    = (float*)  alloc((size_t)4096 * 2 * 4);
  float*   P2     = (float*)  alloc((size_t)5 * 4096 * 2 * 4);
  float*   params = (float*)  alloc(4096);
  float*   dparams= (float*)  alloc(4096);
  if (ws_size < off) return;   // workspace too small: fail visibly (untouched out)

  // c-buffers live in the upper 32 MB of d_out (64 MB total). Each is
  // 32 planes * HW bf16 = 16 MB. cbuf_a spans [32,48) MB, cbuf_b [48,64) MB.
  // All c traffic finishes before k_final, which then rewrites all of out.
  bf16* cbuf_a = (bf16*)(out + 8 * 1024 * 1024);   // byte offset 32 MB
  bf16* cbuf_b = cbuf_a + (size_t)32 * HW;         // +16 MB (32*HW bf16 elems)

  k_quant_pad<<<dim3((6*522*522 + 255)/256), dim3(256), 0, stream>>>(x, qpad);
  k_mode     <<<dim3(768), dim3(256), 0, stream>>>(qpad, xm);
  k_stats1   <<<dim3(512), dim3(256), 0, stream>>>(xm, w1, b1, Pp);
  k_fin_prep <<<dim3(1),   dim3(256), 0, stream>>>(Pp, g1, be1, params, 0, 16);
  k_stats2   <<<dim3(512), dim3(256), 0, stream>>>(xm, w1, b1, w2, b2, params, Pp);
  k_fin_prep <<<dim3(1),   dim3(256), 0, stream>>>(Pp, g2, be2, params, 32, 48);
  k_prep     <<<dim3(512), dim3(256), 0, stream>>>(xm, w1, b1, w2, b2, params, p);
  k_convstat <<<dim3(4096), dim3(256), 0, stream>>>(p, dw, P1a, cbuf_a);

  bf16* cin = cbuf_a; bf16* cout = cbuf_b;
  float* Pin = P1a; float* Pout = P1b;
  for (int t = 0; t < 5; ++t){
    k_bnfused<<<dim3(4096), dim3(256), 0, stream>>>(cin, dw, gd, bd, Pin,
                                                    dbuf[t], cout, P2 + t * 8192,
                                                    Pout, (t < 4) ? 1 : 0);
    bf16* ctmp = cin; cin = cout; cout = ctmp;
    float* tmp = Pin; Pin = Pout; Pout = tmp;
  }
  k_fin_all<<<dim3(20), dim3(256), 0, stream>>>(P2, ww, gw, bw, wh, gh, bh, dparams);
  k_final<<<dim3(2048), dim3(256), 0, stream>>>(p, dbuf[0], dbuf[1], dbuf[2],
                                                dbuf[3], dbuf[4], dparams, out);
}